// Round 1
// 954.832 us; speedup vs baseline: 2.8356x; 2.8356x over previous
//
#include <hip/hip_runtime.h>

typedef __bf16 bf16x8 __attribute__((ext_vector_type(8)));
typedef float  f32x4  __attribute__((ext_vector_type(4)));

#define PS  136   // padded LDS row stride (bf16 elems)
#define MT  32    // nodes per tile (2 x 16-row MFMA subtiles per wave)
#define CPB 16    // crystals per block
#define MFMA(a, b, c) __builtin_amdgcn_mfma_f32_16x16x32_bf16((a), (b), (c), 0, 0, 0)

// bf16 weight pack offsets in d_ws (elements)
#define O_WM1 0
#define O_WM2 65536
#define O_WA1 131072
#define O_WA2 262144
#define W_ELEMS 262656          // * 2 bytes = 525312 B needed in ws

__device__ __forceinline__ bf16x8 cvt8(const float* pf) {
    float4 a = *(const float4*)pf, b = *(const float4*)(pf + 4);
    bf16x8 o;
    o[0] = (__bf16)a.x; o[1] = (__bf16)a.y; o[2] = (__bf16)a.z; o[3] = (__bf16)a.w;
    o[4] = (__bf16)b.x; o[5] = (__bf16)b.y; o[6] = (__bf16)b.z; o[7] = (__bf16)b.w;
    return o;
}

__device__ __forceinline__ int lower_bound(const int* __restrict__ a, int n, int v) {
    int lo = 0, hi = n;
    while (lo < hi) { int mid = (lo + hi) >> 1; if (a[mid] < v) lo = mid + 1; else hi = mid; }
    return lo;
}

// ---------------------------------------------------------------------------
// Prep: pack 4 f32 weight tensors into contiguous bf16 in ws.
// ---------------------------------------------------------------------------
__global__ __launch_bounds__(256) void prep_kernel(
    const float* __restrict__ Wm1, const float* __restrict__ Wm2,
    const float* __restrict__ Wa1, const float* __restrict__ Wa2,
    __bf16* __restrict__ wb)
{
    int i8 = blockIdx.x * 256 + threadIdx.x;
    if (i8 >= W_ELEMS / 8) return;
    int i = i8 * 8;
    const float* src; int s;
    if      (i < O_WM2) { src = Wm1; s = i; }
    else if (i < O_WA1) { src = Wm2; s = i - O_WM2; }
    else if (i < O_WA2) { src = Wa1; s = i - O_WA1; }
    else                { src = Wa2; s = i - O_WA2; }
    *(bf16x8*)(wb + i) = cvt8(src + s);
}

template<bool WB>
__device__ __forceinline__ bf16x8 wfrag(const __bf16* wb, const float* wf, size_t idx) {
    if constexpr (WB) return *(const bf16x8*)(wb + idx);
    else              return cvt8(wf + idx);
}

// ---------------------------------------------------------------------------
// Fused kernel, multi-crystal blocks. Block b owns crystals [b*CPB,(b+1)*CPB).
// Dense MT-node tiles span crystal boundaries; 4 waves = 4 heads; per-tile
// crystal "runs" found by ballot; online softmax with flush on crystal change.
// MFMA 16x16x32 bf16: A[m=lane&15][k=(lane>>4)*8+j]; B=W[n][k] same mapping;
// D: col(n)=lane&15, row(m)=(lane>>4)*4+reg.
// ---------------------------------------------------------------------------
template<bool WB>
__global__ __launch_bounds__(256, 2) void fused2_kernel(
    const float* __restrict__ fea, const float* __restrict__ cry,
    const float* __restrict__ Wm1, const float* __restrict__ bm1,
    const float* __restrict__ Wm2, const float* __restrict__ bm2,
    const float* __restrict__ Wa1, const float* __restrict__ ba1,
    const float* __restrict__ Wa2, const float* __restrict__ ba2,
    const __bf16* __restrict__ wb, const int* __restrict__ index,
    int N, int S, float* __restrict__ out)
{
    __shared__ __align__(16) __bf16 feaT[MT * PS];
    __shared__ __align__(16) __bf16 cryT[CPB * PS];
    __shared__ __align__(16) __bf16 hT[4][MT * PS];
    __shared__ int sidx[64];
    __shared__ int sb[2];

    const int c0 = blockIdx.x * CPB;
    const int c1 = (c0 + CPB < S) ? c0 + CPB : S;
    const int t = threadIdx.x;
    const int lane = t & 63, h = t >> 6, ml = lane & 15, q = lane >> 4;

    if (t == 0)  sb[0] = lower_bound(index, N, c0);
    if (t == 64) sb[1] = lower_bound(index, N, c1);

    // stage this block's crystal features once (rows c0..c1-1)
    {
        int row = t >> 4, colo = (t & 15) * 8;
        if (c0 + row < S)
            *(bf16x8*)&cryT[row * PS + colo] = cvt8(cry + (size_t)(c0 + row) * 128 + colo);
    }
    __syncthreads();
    const int start = sb[0], end = sb[1];

    // hoisted per-lane biases / wa2 (col = ot*16+ml of head h)
    float ba1v[8], bm1v[8], bb2[8], wa2v[8];
#pragma unroll
    for (int ot = 0; ot < 8; ot++) {
        ba1v[ot] = ba1[h * 128 + ot * 16 + ml];
        bm1v[ot] = bm1[h * 128 + ot * 16 + ml];
        bb2[ot]  = bm2[h * 128 + ot * 16 + ml];
        wa2v[ot] = Wa2[h * 128 + ot * 16 + ml];
    }
    const float ba2v = ba2[h];

    float m_run = -1e30f, d_run = 0.f;
    float wacc[8] = {0.f,0.f,0.f,0.f,0.f,0.f,0.f,0.f};
    int cur_c = -1, emit_c = c0;

    auto flushf = [&]() {
        float inv = 1.f / (d_run + 1e-16f);
        for (int z = emit_c; z < cur_c; z++)   // zero-fill empty crystals
            *(float2*)&out[(size_t)z * 512 + h * 128 + lane * 2] = make_float2(0.f, 0.f);
#pragma unroll
        for (int ot = 0; ot < 8; ot++) {
            float v = wacc[ot];
            v += __shfl_xor(v, 16);
            v += __shfl_xor(v, 32);
            if (q == 0) out[(size_t)cur_c * 512 + h * 128 + ot * 16 + ml] = v * inv;
            wacc[ot] = 0.f;
        }
        emit_c = cur_c + 1;
        m_run = -1e30f; d_run = 0.f;
    };

    for (int tb = start; tb < end; tb += MT) {
        int nv = end - tb; if (nv > MT) nv = MT;

        // ---- stage fea tile (f32 -> bf16, zero-pad invalid rows) + sidx ----
        {
            int row = t >> 3, colo = (t & 7) * 16;
            bf16x8 v0, v1;
            if (row < nv) {
                v0 = cvt8(fea + (size_t)(tb + row) * 128 + colo);
                v1 = cvt8(fea + (size_t)(tb + row) * 128 + colo + 8);
            } else {
#pragma unroll
                for (int j = 0; j < 8; j++) { v0[j] = (__bf16)0.f; v1[j] = (__bf16)0.f; }
            }
            *(bf16x8*)&feaT[row * PS + colo]     = v0;
            *(bf16x8*)&feaT[row * PS + colo + 8] = v1;
            if (t < 64) sidx[t] = (t < nv) ? index[tb + t] : 0x7fffffff;
        }
        __syncthreads();

        // ---- A fragments (fea + per-row gathered cry) ----
        bf16x8 afA[2][4], afC[2][4];
        int crow[2];
#pragma unroll
        for (int s = 0; s < 2; s++) {
            int sv = sidx[s * 16 + ml];
            crow[s] = (sv == 0x7fffffff) ? 0 : (sv - c0);
        }
#pragma unroll
        for (int s = 0; s < 2; s++)
#pragma unroll
        for (int k = 0; k < 4; k++) {
            afA[s][k] = *(bf16x8*)&feaT[(s * 16 + ml) * PS + k * 32 + q * 8];
            afC[s][k] = *(bf16x8*)&cryT[crow[s] * PS + k * 32 + q * 8];
        }

        // ---- GEMM3 + in-register logits: l = wa2 . leaky(a_in@Wa1^T+ba1) + ba2 ----
        float lsum[8] = {0.f,0.f,0.f,0.f,0.f,0.f,0.f,0.f};
#pragma unroll
        for (int ot = 0; ot < 8; ot++) {
            size_t wrow = (size_t)h * 32768 + (size_t)(ot * 16 + ml) * 256;
            f32x4 a0 = {0.f,0.f,0.f,0.f}, a1 = {0.f,0.f,0.f,0.f};
#pragma unroll
            for (int k = 0; k < 4; k++) {
                bf16x8 B = wfrag<WB>(wb + O_WA1, Wa1, wrow + k * 32 + q * 8);
                a0 = MFMA(afA[0][k], B, a0);
                a1 = MFMA(afA[1][k], B, a1);
            }
#pragma unroll
            for (int k = 0; k < 4; k++) {
                bf16x8 B = wfrag<WB>(wb + O_WA1, Wa1, wrow + 128 + k * 32 + q * 8);
                a0 = MFMA(afC[0][k], B, a0);
                a1 = MFMA(afC[1][k], B, a1);
            }
#pragma unroll
            for (int r = 0; r < 4; r++) {
                float v0 = a0[r] + ba1v[ot]; v0 = v0 >= 0.f ? v0 : 0.01f * v0;
                float v1 = a1[r] + ba1v[ot]; v1 = v1 >= 0.f ? v1 : 0.01f * v1;
                lsum[r]     += v0 * wa2v[ot];
                lsum[4 + r] += v1 * wa2v[ot];
            }
        }
        float lv[8];
#pragma unroll
        for (int sl = 0; sl < 8; sl++) {
            float x = lsum[sl];
            x += __shfl_xor(x, 1);
            x += __shfl_xor(x, 2);
            x += __shfl_xor(x, 4);
            x += __shfl_xor(x, 8);
            lv[sl] = x + ba2v;   // logit of row (sl>>2)*16 + q*4 + (sl&3), replicated over ml
        }

        // ---- GEMM1: H1 = leaky(fea @ Wm1^T + bm1) -> per-wave hT ----
#pragma unroll
        for (int ot = 0; ot < 8; ot++) {
            size_t wrow = (size_t)h * 16384 + (size_t)(ot * 16 + ml) * 128;
            f32x4 a0 = {0.f,0.f,0.f,0.f}, a1 = {0.f,0.f,0.f,0.f};
#pragma unroll
            for (int k = 0; k < 4; k++) {
                bf16x8 B = wfrag<WB>(wb + O_WM1, Wm1, wrow + k * 32 + q * 8);
                a0 = MFMA(afA[0][k], B, a0);
                a1 = MFMA(afA[1][k], B, a1);
            }
#pragma unroll
            for (int r = 0; r < 4; r++) {
                float v0 = a0[r] + bm1v[ot]; v0 = v0 >= 0.f ? v0 : 0.01f * v0;
                float v1 = a1[r] + bm1v[ot]; v1 = v1 >= 0.f ? v1 : 0.01f * v1;
                hT[h][(q * 4 + r) * PS + ot * 16 + ml]        = (__bf16)v0;
                hT[h][(16 + q * 4 + r) * PS + ot * 16 + ml]   = (__bf16)v1;
            }
        }

        // ---- GEMM2: m = H1 @ Wm2^T + bm2 (bias folded), kept in registers ----
        bf16x8 a2[2][4];
#pragma unroll
        for (int s = 0; s < 2; s++)
#pragma unroll
        for (int k = 0; k < 4; k++)
            a2[s][k] = *(bf16x8*)&hT[h][(s * 16 + ml) * PS + k * 32 + q * 8];
        f32x4 acc2[2][8];
#pragma unroll
        for (int ot = 0; ot < 8; ot++) {
            size_t wrow = (size_t)h * 16384 + (size_t)(ot * 16 + ml) * 128;
            f32x4 a0 = {0.f,0.f,0.f,0.f}, a1 = {0.f,0.f,0.f,0.f};
#pragma unroll
            for (int k = 0; k < 4; k++) {
                bf16x8 B = wfrag<WB>(wb + O_WM2, Wm2, wrow + k * 32 + q * 8);
                a0 = MFMA(a2[0][k], B, a0);
                a1 = MFMA(a2[1][k], B, a1);
            }
#pragma unroll
            for (int r = 0; r < 4; r++) { a0[r] += bb2[ot]; a1[r] += bb2[ot]; }
            acc2[0][ot] = a0; acc2[1][ot] = a1;
        }

        // ---- run walk: per-crystal online softmax + weighted accumulation ----
        unsigned long long bmask;
        {
            int svl = (lane < nv) ? sidx[lane] : -2;
            int svp = (lane > 0 && lane < nv) ? sidx[lane - 1] : -1;
            bmask = __ballot(lane < nv && (lane == 0 || svl != svp));
        }
        while (bmask) {
            int a = (int)__builtin_ctzll(bmask);
            bmask &= bmask - 1;
            int b = bmask ? (int)__builtin_ctzll(bmask) : nv;
            int c = sidx[a];
            if (c != cur_c) {
                if (cur_c >= 0) flushf();
                cur_c = c;
            }
            float tmax = -1e30f;
#pragma unroll
            for (int sl = 0; sl < 8; sl++) {
                int row = (sl >> 2) * 16 + q * 4 + (sl & 3);
                if (row >= a && row < b) tmax = fmaxf(tmax, lv[sl]);
            }
            tmax = fmaxf(tmax, __shfl_xor(tmax, 16));
            tmax = fmaxf(tmax, __shfl_xor(tmax, 32));
            float m_new = fmaxf(m_run, tmax);
            float scf = __expf(m_run - m_new);
            d_run *= scf;
#pragma unroll
            for (int ot = 0; ot < 8; ot++) wacc[ot] *= scf;
            m_run = m_new;

            float wv[8]; float dp = 0.f;
#pragma unroll
            for (int sl = 0; sl < 8; sl++) {
                int row = (sl >> 2) * 16 + q * 4 + (sl & 3);
                float w = (row >= a && row < b) ? __expf(lv[sl] - m_run) : 0.f;
                wv[sl] = w; dp += w;
            }
            dp += __shfl_xor(dp, 16);
            dp += __shfl_xor(dp, 32);
            d_run += dp;
#pragma unroll
            for (int ot = 0; ot < 8; ot++) {
                float s = 0.f;
#pragma unroll
                for (int sl = 0; sl < 8; sl++)
                    s += wv[sl] * acc2[sl >> 2][ot][sl & 3];
                wacc[ot] += s;
            }
        }
        __syncthreads();   // protect feaT/sidx before next tile's staging
    }

    if (cur_c >= 0) flushf();
    for (int z = emit_c; z < c1; z++)   // trailing empty crystals
        *(float2*)&out[(size_t)z * 512 + h * 128 + lane * 2] = make_float2(0.f, 0.f);
}

// ---------------------------------------------------------------------------
extern "C" void kernel_launch(void* const* d_in, const int* in_sizes, int n_in,
                              void* d_out, int out_size, void* d_ws, size_t ws_size,
                              hipStream_t stream)
{
    const float* fea = (const float*)d_in[0];
    const float* cry = (const float*)d_in[1];
    const float* Wm1 = (const float*)d_in[2];
    const float* bm1 = (const float*)d_in[3];
    const float* Wm2 = (const float*)d_in[4];
    const float* bm2 = (const float*)d_in[5];
    const float* Wa1 = (const float*)d_in[6];
    const float* ba1 = (const float*)d_in[7];
    const float* Wa2 = (const float*)d_in[8];
    const float* ba2 = (const float*)d_in[9];
    const int* index = (const int*)d_in[10];

    const int N = in_sizes[0] / 128;      // 200000
    const int S = out_size / 512;         // 16384
    const int grid = (S + CPB - 1) / CPB;

    if (ws_size >= (size_t)W_ELEMS * 2) {
        __bf16* wb = (__bf16*)d_ws;
        prep_kernel<<<(W_ELEMS / 8 + 255) / 256, 256, 0, stream>>>(Wm1, Wm2, Wa1, Wa2, wb);
        fused2_kernel<true><<<grid, 256, 0, stream>>>(fea, cry, Wm1, bm1, Wm2, bm2,
                                                      Wa1, ba1, Wa2, ba2, wb, index,
                                                      N, S, (float*)d_out);
    } else {
        fused2_kernel<false><<<grid, 256, 0, stream>>>(fea, cry, Wm1, bm1, Wm2, bm2,
                                                       Wa1, ba1, Wa2, ba2, nullptr, index,
                                                       N, S, (float*)d_out);
    }
}